// Round 1
// baseline (179.493 us; speedup 1.0000x reference)
//
#include <hip/hip_runtime.h>
#include <hip/hip_bf16.h>
#include <stdint.h>

#define T_TOKENS 8192
#define F_DIM    2048
#define E_EXP    16
#define R_RANK   16
#define O_DIM    2048
#define KDIM     (E_EXP * R_RANK)   // 256

typedef short v8s __attribute__((ext_vector_type(8)));
typedef float v4f __attribute__((ext_vector_type(4)));

#define AS1 __attribute__((address_space(1)))
#define AS3 __attribute__((address_space(3)))

__device__ __forceinline__ uint16_t f2bf(float f) {
  uint32_t u = __builtin_bit_cast(uint32_t, f);
  u += 0x7fffu + ((u >> 16) & 1u);   // round-to-nearest-even
  return (uint16_t)(u >> 16);
}

// async global->LDS, 16B per lane; LDS dest = wave-uniform base + lane*16
__device__ __forceinline__ void g2lds16(const uint16_t* g, uint16_t* l) {
  __builtin_amdgcn_global_load_lds((AS1 void*)g, (AS3 void*)l, 16, 0, 0);
}

// ---------------------------------------------------------------------------
// K1: streaming x->bf16 + partial sims (chunked; fp32 16-elem lane chains).
// Partials layout: float4 partials4[(c*4+e4)*8192 + t]  (coalesced R+W).
// Folded-in weight prep (grid-y >= 128, 64 blocks): cast A_stack -> bf16;
// gather-transpose B_stack (E,O,R) -> Bb (O,K) bf16.
// ---------------------------------------------------------------------------
__global__ __launch_bounds__(256) void route_stream(
    const float* __restrict__ x, const float* __restrict__ P,
    const float* __restrict__ A, const float* __restrict__ Bst,
    uint16_t* __restrict__ xb, float4* __restrict__ partials4,
    uint16_t* __restrict__ Ab, uint16_t* __restrict__ Bb) {
  __shared__ float ps[16 * 260];
  const int tid = threadIdx.x;
  const int c   = blockIdx.x;
  const int by  = blockIdx.y;

  if (by >= 128) {
    // ---- weight prep path: 64 blocks x 256 threads, grid-stride ----
    const int gid = ((by - 128) * 8 + c) * 256 + tid;
    for (int i = gid; i < KDIM * F_DIM; i += 64 * 256)
      Ab[i] = f2bf(A[i]);
    for (int i = gid; i < O_DIM * KDIM; i += 64 * 256) {
      const int k = i & (KDIM - 1);
      const int o = i >> 8;
      const int e = k >> 4, r = k & 15;
      Bb[i] = f2bf(Bst[((size_t)e * O_DIM + o) * R_RANK + r]);
    }
    return;
  }

  const int f0 = c * 256;
  {
    const int e = tid >> 4;
    #pragma unroll
    for (int j = 0; j < 4; ++j) {
      const int col = (tid & 15) * 4 + j * 64;
      *(float4*)&ps[e * 260 + col] =
          *(const float4*)&P[(size_t)e * F_DIM + f0 + col];
    }
  }
  __syncthreads();

  const int sub = tid & 15;
  const int tg  = tid >> 4;
  const int t0  = by * 64 + tg * 4;
  const float* xr = x + (size_t)t0 * F_DIM + f0;
  uint16_t*    xw = xb + (size_t)t0 * F_DIM + f0;

  float a0[16], a1[16], a2[16], a3[16];
  #pragma unroll
  for (int e = 0; e < 16; ++e) { a0[e] = 0.f; a1[e] = 0.f; a2[e] = 0.f; a3[e] = 0.f; }

  #pragma unroll
  for (int j = 0; j < 4; ++j) {
    const int off = sub * 4 + j * 64;
    float4 v0 = *(const float4*)&xr[off];
    float4 v1 = *(const float4*)&xr[F_DIM + off];
    float4 v2 = *(const float4*)&xr[2 * F_DIM + off];
    float4 v3 = *(const float4*)&xr[3 * F_DIM + off];
    uint2 p0, p1, p2, p3;
    p0.x = (uint32_t)f2bf(v0.x) | ((uint32_t)f2bf(v0.y) << 16);
    p0.y = (uint32_t)f2bf(v0.z) | ((uint32_t)f2bf(v0.w) << 16);
    p1.x = (uint32_t)f2bf(v1.x) | ((uint32_t)f2bf(v1.y) << 16);
    p1.y = (uint32_t)f2bf(v1.z) | ((uint32_t)f2bf(v1.w) << 16);
    p2.x = (uint32_t)f2bf(v2.x) | ((uint32_t)f2bf(v2.y) << 16);
    p2.y = (uint32_t)f2bf(v2.z) | ((uint32_t)f2bf(v2.w) << 16);
    p3.x = (uint32_t)f2bf(v3.x) | ((uint32_t)f2bf(v3.y) << 16);
    p3.y = (uint32_t)f2bf(v3.z) | ((uint32_t)f2bf(v3.w) << 16);
    *(uint2*)&xw[off]             = p0;
    *(uint2*)&xw[F_DIM + off]     = p1;
    *(uint2*)&xw[2 * F_DIM + off] = p2;
    *(uint2*)&xw[3 * F_DIM + off] = p3;
    #pragma unroll
    for (int e = 0; e < 16; ++e) {
      float4 pv = *(float4*)&ps[e * 260 + off];
      a0[e] += v0.x * pv.x; a0[e] += v0.y * pv.y; a0[e] += v0.z * pv.z; a0[e] += v0.w * pv.w;
      a1[e] += v1.x * pv.x; a1[e] += v1.y * pv.y; a1[e] += v1.z * pv.z; a1[e] += v1.w * pv.w;
      a2[e] += v2.x * pv.x; a2[e] += v2.y * pv.y; a2[e] += v2.z * pv.z; a2[e] += v2.w * pv.w;
      a3[e] += v3.x * pv.x; a3[e] += v3.y * pv.y; a3[e] += v3.z * pv.z; a3[e] += v3.w * pv.w;
    }
  }

  #pragma unroll
  for (int e = 0; e < 16; ++e) {
    #pragma unroll
    for (int m = 1; m < 16; m <<= 1) {
      a0[e] += __shfl_xor(a0[e], m, 64);
      a1[e] += __shfl_xor(a1[e], m, 64);
      a2[e] += __shfl_xor(a2[e], m, 64);
      a3[e] += __shfl_xor(a3[e], m, 64);
    }
  }

  const size_t cb = (size_t)c * 4;
  if (sub == 0) {
    #pragma unroll
    for (int e4 = 0; e4 < 4; ++e4)
      partials4[(cb + e4) * T_TOKENS + t0] =
          make_float4(a0[e4 * 4], a0[e4 * 4 + 1], a0[e4 * 4 + 2], a0[e4 * 4 + 3]);
  } else if (sub == 1) {
    #pragma unroll
    for (int e4 = 0; e4 < 4; ++e4)
      partials4[(cb + e4) * T_TOKENS + t0 + 1] =
          make_float4(a1[e4 * 4], a1[e4 * 4 + 1], a1[e4 * 4 + 2], a1[e4 * 4 + 3]);
  } else if (sub == 2) {
    #pragma unroll
    for (int e4 = 0; e4 < 4; ++e4)
      partials4[(cb + e4) * T_TOKENS + t0 + 2] =
          make_float4(a2[e4 * 4], a2[e4 * 4 + 1], a2[e4 * 4 + 2], a2[e4 * 4 + 3]);
  } else if (sub == 3) {
    #pragma unroll
    for (int e4 = 0; e4 < 4; ++e4)
      partials4[(cb + e4) * T_TOKENS + t0 + 3] =
          make_float4(a3[e4 * 4], a3[e4 * 4 + 1], a3[e4 * 4 + 2], a3[e4 * 4 + 3]);
  }
}

// ---------------------------------------------------------------------------
// K2: gemm_xa, 64x64 tile, DOUBLE-BUFFERED BK=64 ping-pong (T3-minimum):
// per sub-step: barrier -> issue next-tile global_load_lds -> compute current.
// Load latency hides under the MFMA phase instead of a full vmcnt(0) stall.
// XCD-swizzled linear grid; topk folded into prologue (tid<64: fp64
// cross-chunk sum + topk + softmax -> coeffL) overlapping the first stage.
// ---------------------------------------------------------------------------
__global__ __launch_bounds__(256) void gemm_xa(
    const uint16_t* __restrict__ xb, const uint16_t* __restrict__ Ab,
    const float4* __restrict__ partials4, const float* __restrict__ scaling,
    const int* __restrict__ topk, uint16_t* __restrict__ wb) {
  __shared__ uint16_t S[16384];   // 32 KB: X ping/pong + A ping/pong
  __shared__ float coeffL[64 * 17];
  uint16_t* X0 = S;
  uint16_t* X1 = S + 4096;
  uint16_t* A0 = S + 8192;
  uint16_t* A1 = S + 12288;
  const int tid  = threadIdx.x;
  const int b    = blockIdx.x;                       // 512 blocks
  const int m_idx = (b & 7) + ((b >> 5) << 3);       // 0..127 (same-XCD share m)
  const int n_idx = (b >> 3) & 3;                    // 0..3
  const int m0 = m_idx * 64, n0 = n_idx * 64;
  const int lane = tid & 63;
  const int wid  = tid >> 6;
  const int wm   = (wid >> 1) * 32;
  const int wn   = (wid & 1) * 32;
  const int quad = lane >> 4;
  const int cl   = lane & 15;

  // staging addresses (pre-swizzled global source, linear LDS dest)
  const int G0 = wid * 64 + lane;
  const int G1 = G0 + 256;
  const int r0 = G0 >> 3, g0 = (G0 & 7) ^ (r0 & 7);
  const int r1 = G1 >> 3, g1 = (G1 & 7) ^ (r1 & 7);
  const uint16_t* xs0 = xb + (size_t)(m0 + r0) * F_DIM + g0 * 8;
  const uint16_t* xs1 = xb + (size_t)(m0 + r1) * F_DIM + g1 * 8;
  const uint16_t* as0 = Ab + (size_t)(n0 + r0) * F_DIM + g0 * 8;
  const uint16_t* as1 = Ab + (size_t)(n0 + r1) * F_DIM + g1 * 8;
  const int d0 = wid * 512;
  const int d1 = wid * 512 + 2048;

  const int ma0 = wm + cl, ma1 = wm + 16 + cl;
  const int nb0 = wn + cl, nb1 = wn + 16 + cl;

#define STAGE_XA(Xb_, Ab_, kk) do {       \
    g2lds16(xs0 + (kk), (Xb_) + d0);      \
    g2lds16(xs1 + (kk), (Xb_) + d1);      \
    g2lds16(as0 + (kk), (Ab_) + d0);      \
    g2lds16(as1 + (kk), (Ab_) + d1);      \
  } while (0)

#define COMP_XA(Xb_, Ab_) do {                                                            \
    _Pragma("unroll")                                                                     \
    for (int ks = 0; ks < 2; ++ks) {                                                      \
      const int gk = ks * 4 + quad;                                                       \
      v8s fa0 = *(v8s*)&(Xb_)[(ma0 * 8 + (gk ^ (ma0 & 7))) * 8];                          \
      v8s fa1 = *(v8s*)&(Xb_)[(ma1 * 8 + (gk ^ (ma1 & 7))) * 8];                          \
      v8s fb0 = *(v8s*)&(Ab_)[(nb0 * 8 + (gk ^ (nb0 & 7))) * 8];                          \
      v8s fb1 = *(v8s*)&(Ab_)[(nb1 * 8 + (gk ^ (nb1 & 7))) * 8];                          \
      acc[0][0] = __builtin_amdgcn_mfma_f32_16x16x32_bf16(fa0, fb0, acc[0][0], 0, 0, 0);  \
      acc[0][1] = __builtin_amdgcn_mfma_f32_16x16x32_bf16(fa0, fb1, acc[0][1], 0, 0, 0);  \
      acc[1][0] = __builtin_amdgcn_mfma_f32_16x16x32_bf16(fa1, fb0, acc[1][0], 0, 0, 0);  \
      acc[1][1] = __builtin_amdgcn_mfma_f32_16x16x32_bf16(fa1, fb1, acc[1][1], 0, 0, 0);  \
    }                                                                                     \
  } while (0)

  v4f acc[2][2];
  #pragma unroll
  for (int i = 0; i < 2; i++)
    #pragma unroll
    for (int j = 0; j < 2; j++) acc[i][j] = (v4f){0.f, 0.f, 0.f, 0.f};

  // prologue stage: first 64-col tile in flight while routing math runs
  STAGE_XA(X0, A0, 0);

  // ---- routing prologue: tokens m0..m0+63 (wave 0 only; overlaps loads) ----
  if (tid < 64) {
    const int t = m0 + tid;
    double s[16];
    #pragma unroll
    for (int e = 0; e < 16; ++e) s[e] = 0.0;
    for (int c = 0; c < 8; ++c) {
      #pragma unroll
      for (int e4 = 0; e4 < 4; ++e4) {
        float4 p = partials4[((size_t)c * 4 + e4) * T_TOKENS + t];
        s[e4 * 4]     += (double)p.x;
        s[e4 * 4 + 1] += (double)p.y;
        s[e4 * 4 + 2] += (double)p.z;
        s[e4 * 4 + 3] += (double)p.w;
      }
    }
    double v[16];
    #pragma unroll
    for (int e = 0; e < 16; ++e) v[e] = fabs(s[e]);
    int k = topk[0];
    if (k > 16) k = 16;
    if (k < 1)  k = 1;
    unsigned mask = 0;
    double mx = 0.0;
    float ssum = 0.f;
    for (int i = 0; i < k; ++i) {
      double bv = -1.0; int bj = 0;
      #pragma unroll
      for (int j = 0; j < 16; ++j) {
        bool ok = !((mask >> j) & 1u) && (v[j] > bv);
        bv = ok ? v[j] : bv;
        bj = ok ? j  : bj;
      }
      mask |= 1u << bj;
      if (i == 0) mx = bv;
      ssum += expf((float)(bv - mx));
    }
    const float sc = scaling[0];
    #pragma unroll
    for (int j = 0; j < 16; ++j)
      coeffL[tid * 17 + j] = ((mask >> j) & 1u)
          ? expf((float)(v[j] - mx)) / ssum * sc : 0.f;
  }

  // ---- K loop: 16 x (two 64-col ping-pong sub-steps) ----
  for (int k0 = 0; k0 < F_DIM; k0 += 128) {
    __syncthreads();                       // drains stage of X0/A0 (cols k0)
    STAGE_XA(X1, A1, k0 + 64);             // prefetch odd half (always valid)
    COMP_XA(X0, A0);
    __syncthreads();                       // drains stage of X1/A1
    if (k0 + 128 < F_DIM) STAGE_XA(X0, A0, k0 + 128);   // prefetch next even
    COMP_XA(X1, A1);
  }

  // epilogue: coeff fold + bf16 pack via LDS bounce, 128B-contiguous stores
  __syncthreads();
  uint16_t* tile = S;   // stride 72
  #pragma unroll
  for (int mi = 0; mi < 2; mi++)
    #pragma unroll
    for (int ni = 0; ni < 2; ni++) {
      const int nl = wn + ni * 16 + cl;
      const int eidx = (n0 + nl) >> 4;
      #pragma unroll
      for (int reg = 0; reg < 4; reg++) {
        const int tl = wm + mi * 16 + quad * 4 + reg;
        float wv = acc[mi][ni][reg] * coeffL[tl * 17 + eidx];
        tile[tl * 72 + nl] = f2bf(wv);
      }
    }
  __syncthreads();
  #pragma unroll
  for (int p = 0; p < 2; ++p) {
    const int row  = p * 32 + (tid >> 3);
    const int colg = (tid & 7) * 8;
    uint4 val = *(uint4*)&tile[row * 72 + colg];
    *(uint4*)&wb[(size_t)(m0 + row) * KDIM + n0 + colg] = val;
  }
#undef STAGE_XA
#undef COMP_XA
}

// ---------------------------------------------------------------------------
// K3: gemm_wb, 64x256 tile (acc[2][8]/wave), BK=64 (4 iters), XCD-swizzled,
// two-pass fp32 LDS-bounce epilogue with 1KB-contiguous stores.
// ---------------------------------------------------------------------------
__global__ __launch_bounds__(256) void gemm_wb(
    const uint16_t* __restrict__ wbuf, const uint16_t* __restrict__ Bb,
    float* __restrict__ out) {
  __shared__ uint16_t S[20480];   // 40 KB: Ws 8 KB + Bs 32 KB
  uint16_t* Ws = S;               // 64 rows x 8 granules
  uint16_t* Bs = S + 4096;        // 256 rows x 8 granules
  const int tid  = threadIdx.x;
  const int b    = blockIdx.x;                       // 1024 blocks
  const int m_idx = (b & 7) + ((b >> 6) << 3);       // 0..127
  const int n_idx = (b >> 3) & 7;                    // 0..7
  const int m0 = m_idx * 64;
  const int n0 = n_idx * 256;
  const int lane = tid & 63;
  const int wid  = tid >> 6;
  const int wm   = (wid >> 1) * 32;
  const int wn   = (wid & 1) * 128;
  const int quad = lane >> 4;
  const int cl   = lane & 15;

  // W staging: 512 granules (2/thread)
  const int GW0 = wid * 64 + lane;
  const int GW1 = GW0 + 256;
  const int wr0 = GW0 >> 3, wg0 = (GW0 & 7) ^ (wr0 & 7);
  const int wr1 = GW1 >> 3, wg1 = (GW1 & 7) ^ (wr1 & 7);
  const uint16_t* wsrc0 = wbuf + (size_t)(m0 + wr0) * KDIM + wg0 * 8;
  const uint16_t* wsrc1 = wbuf + (size_t)(m0 + wr1) * KDIM + wg1 * 8;

  // B staging: 2048 granules (8/thread)
  const uint16_t* bsrc[8];
  #pragma unroll
  for (int p = 0; p < 8; ++p) {
    const int G = p * 256 + wid * 64 + lane;
    const int r = G >> 3, g = (G & 7) ^ (r & 7);
    bsrc[p] = Bb + (size_t)(n0 + r) * KDIM + g * 8;
  }

  v4f acc[2][8];
  #pragma unroll
  for (int i = 0; i < 2; i++)
    #pragma unroll
    for (int j = 0; j < 8; j++) acc[i][j] = (v4f){0.f, 0.f, 0.f, 0.f};

  const int ma0 = wm + cl, ma1 = wm + 16 + cl;

  #pragma unroll
  for (int k0 = 0; k0 < KDIM; k0 += 64) {
    __syncthreads();
    g2lds16(wsrc0 + k0, Ws + wid * 512);
    g2lds16(wsrc1 + k0, Ws + wid * 512 + 2048);
    #pragma unroll
    for (int p = 0; p < 8; ++p)
      g2lds16(bsrc[p] + k0, Bs + (p * 256 + wid * 64) * 8);
    __syncthreads();
    #pragma unroll
    for (int ks = 0; ks < 2; ++ks) {
      const int gk = ks * 4 + quad;
      v8s fa0 = *(v8s*)&Ws[(ma0 * 8 + (gk ^ (ma0 & 7))) * 8];
      v8s fa1 = *(v8s*)&Ws[(ma1 * 8 + (gk ^ (ma1 & 7))) * 8];
      v8s fb[8];
      #pragma unroll
      for (int j = 0; j < 8; ++j) {
        const int nb = wn + j * 16 + cl;
        fb[j] = *(v8s*)&Bs[(nb * 8 + (gk ^ (nb & 7))) * 8];
      }
      #pragma unroll
      for (int j = 0; j < 8; ++j) {
        acc[0][j] = __builtin_amdgcn_mfma_f32_16x16x32_bf16(fa0, fb[j], acc[0][j], 0, 0, 0);
        acc[1][j] = __builtin_amdgcn_mfma_f32_16x16x32_bf16(fa1, fb[j], acc[1][j], 0, 0, 0);
      }
    }
  }

  // epilogue: two half-tiles (32 rows each) through fp32 LDS bounce
  float* ft = (float*)S;   // 32 x 260 floats = 33.3 KB <= 40 KB
  #pragma unroll
  for (int h = 0; h < 2; ++h) {
    __syncthreads();
    if ((wid >> 1) == h) {
      #pragma unroll
      for (int mi = 0; mi < 2; mi++)
        #pragma unroll
        for (int j = 0; j < 8; j++) {
          const int col = wn + j * 16 + cl;
          #pragma unroll
          for (int reg = 0; reg < 4; reg++) {
            const int rl = mi * 16 + quad * 4 + reg;   // 0..31
            ft[rl * 260 + col] = acc[mi][j][reg];
          }
        }
    }
    __syncthreads();
    #pragma unroll
    for (int p = 0; p < 8; ++p) {
      const int f4  = p * 256 + tid;     // 0..2047
      const int row = f4 >> 6;           // 0..31
      const int c4  = f4 & 63;
      float4 v = *(float4*)&ft[row * 260 + c4 * 4];
      *(float4*)&out[(size_t)(m0 + h * 32 + row) * O_DIM + n0 + c4 * 4] = v;
    }
  }
}

extern "C" void kernel_launch(void* const* d_in, const int* in_sizes, int n_in,
                              void* d_out, int out_size, void* d_ws, size_t ws_size,
                              hipStream_t stream) {
  (void)in_sizes; (void)n_in; (void)out_size; (void)ws_size;
  const float* x       = (const float*)d_in[0];
  const float* P       = (const float*)d_in[1];
  const float* A       = (const float*)d_in[2];
  const float* Bst     = (const float*)d_in[3];
  const float* scaling = (const float*)d_in[4];
  const int*   topk    = (const int*)d_in[5];
  float* out = (float*)d_out;

  char* ws = (char*)d_ws;
  uint16_t* xb     = (uint16_t*)(ws);                 // 33,554,432 B
  uint16_t* Ab     = (uint16_t*)(ws + 33554432);      //  1,048,576 B
  uint16_t* Bb     = (uint16_t*)(ws + 34603008);      //  1,048,576 B
  uint16_t* wbuf   = (uint16_t*)(ws + 35651584);      //  4,194,304 B
  float4*   parts  = (float4*)  (ws + 39845888);      //  4,194,304 B (no alias)

  // route grid: y<128 = streaming route; y>=128 (64 blocks) = weight prep
  hipLaunchKernelGGL(route_stream, dim3(8, 136), dim3(256), 0, stream,
                     x, P, A, Bst, xb, parts, Ab, Bb);
  hipLaunchKernelGGL(gemm_xa, dim3(512), dim3(256), 0, stream,
                     xb, Ab, parts, scaling, topk, wbuf);
  hipLaunchKernelGGL(gemm_wb, dim3(1024), dim3(256), 0, stream, wbuf, Bb, out);
}